// Round 1
// baseline (2817.420 us; speedup 1.0000x reference)
//
#include <hip/hip_runtime.h>

// GraphConvolution: out = relu(bias + sum_k S_k @ (x @ W_k))
// B=4, N=50000, F_IN=F_OUT=64, K=4, E=800000 (derived from in_sizes where possible)

#define FDIM 64

// ---------------------------------------------------------------------------
// h = x @ W   x:[M,64] f32, W:[64,64] f32, h:[M,64] f32.  M % 64 == 0 assumed
// (M = 200000 = 3125*64). One block = 64 rows of output.
// ---------------------------------------------------------------------------
__global__ __launch_bounds__(256) void gemm64(
    const float* __restrict__ x, const float* __restrict__ W,
    float* __restrict__ h, int M)
{
    __shared__ float xs[64][68];   // transposed x tile: xs[f][r], padded (272B row, 16B aligned)
    __shared__ float Wl[64][64];   // W[f][g]

    const int t = threadIdx.x;

    // load W: 4096 floats = 1024 float4, 256 threads x 4
    {
        const float4* Wv = (const float4*)W;
        float4* Wd = (float4*)&Wl[0][0];
#pragma unroll
        for (int i = 0; i < 4; ++i) Wd[t + 256 * i] = Wv[t + 256 * i];
    }

    const int row0 = blockIdx.x * 64;

    // load x tile (coalesced float4), store transposed into xs
#pragma unroll
    for (int i = 0; i < 4; ++i) {
        int idx = t + 256 * i;        // 0..1023 float4 slots
        int r = idx >> 4;             // row in tile 0..63
        int c4 = idx & 15;            // float4 column
        float4 v = ((const float4*)(x + (size_t)(row0 + r) * FDIM))[c4];
        int f = c4 * 4;
        xs[f + 0][r] = v.x;
        xs[f + 1][r] = v.y;
        xs[f + 2][r] = v.z;
        xs[f + 3][r] = v.w;
    }
    __syncthreads();

    // each thread: 4 rows x 4 cols register tile
    const int r0 = (t >> 4) * 4;     // 0,4,..,60
    const int g0 = (t & 15) * 4;     // 0,4,..,60

    float acc[4][4];
#pragma unroll
    for (int i = 0; i < 4; ++i)
#pragma unroll
        for (int j = 0; j < 4; ++j) acc[i][j] = 0.f;

#pragma unroll
    for (int f = 0; f < 64; ++f) {
        float4 xv = *(const float4*)&xs[f][r0];
        float4 wv = *(const float4*)&Wl[f][g0];
        acc[0][0] = fmaf(xv.x, wv.x, acc[0][0]);
        acc[0][1] = fmaf(xv.x, wv.y, acc[0][1]);
        acc[0][2] = fmaf(xv.x, wv.z, acc[0][2]);
        acc[0][3] = fmaf(xv.x, wv.w, acc[0][3]);
        acc[1][0] = fmaf(xv.y, wv.x, acc[1][0]);
        acc[1][1] = fmaf(xv.y, wv.y, acc[1][1]);
        acc[1][2] = fmaf(xv.y, wv.z, acc[1][2]);
        acc[1][3] = fmaf(xv.y, wv.w, acc[1][3]);
        acc[2][0] = fmaf(xv.z, wv.x, acc[2][0]);
        acc[2][1] = fmaf(xv.z, wv.y, acc[2][1]);
        acc[2][2] = fmaf(xv.z, wv.z, acc[2][2]);
        acc[2][3] = fmaf(xv.z, wv.w, acc[2][3]);
        acc[3][0] = fmaf(xv.w, wv.x, acc[3][0]);
        acc[3][1] = fmaf(xv.w, wv.y, acc[3][1]);
        acc[3][2] = fmaf(xv.w, wv.z, acc[3][2]);
        acc[3][3] = fmaf(xv.w, wv.w, acc[3][3]);
    }

#pragma unroll
    for (int i = 0; i < 4; ++i) {
        *(float4*)(h + (size_t)(row0 + r0 + i) * FDIM + g0) =
            make_float4(acc[i][0], acc[i][1], acc[i][2], acc[i][3]);
    }
}

// ---------------------------------------------------------------------------
// scatter: one wave per edge. lane = g (0..63); loop over b.
// out[b, row, g] += val * h[b, col, g]
// ---------------------------------------------------------------------------
__global__ __launch_bounds__(256) void scatter_edges(
    const float* __restrict__ h,
    const int* __restrict__ rows,
    const int* __restrict__ cols,
    const float* __restrict__ vals,
    float* __restrict__ out,
    int E, int N)
{
    const int e = (blockIdx.x << 2) | (threadIdx.x >> 6);
    if (e >= E) return;
    const int lane = threadIdx.x & 63;

    const int row = __builtin_amdgcn_readfirstlane(rows[e]);
    const int col = __builtin_amdgcn_readfirstlane(cols[e]);
    const float val =
        __uint_as_float(__builtin_amdgcn_readfirstlane(__float_as_uint(vals[e])));

    const size_t stride = (size_t)N * FDIM;   // per-b stride
    size_t cbase = (size_t)col * FDIM + lane;
    size_t rbase = (size_t)row * FDIM + lane;

#pragma unroll
    for (int b = 0; b < 4; ++b) {
        float hv = h[cbase + (size_t)b * stride];
        atomicAdd(out + rbase + (size_t)b * stride, hv * val);
    }
}

// ---------------------------------------------------------------------------
// out = relu(out + bias), float4 over [B*N, 64]
// ---------------------------------------------------------------------------
__global__ __launch_bounds__(256) void bias_relu(
    float* __restrict__ out, const float* __restrict__ bias, size_t total4)
{
    size_t i = (size_t)blockIdx.x * blockDim.x + threadIdx.x;
    if (i >= total4) return;
    float4 v = ((float4*)out)[i];
    float4 b = ((const float4*)bias)[i & 15];   // 64 floats = 16 float4, g = (i%16)*4..
    v.x = fmaxf(v.x + b.x, 0.f);
    v.y = fmaxf(v.y + b.y, 0.f);
    v.z = fmaxf(v.z + b.z, 0.f);
    v.w = fmaxf(v.w + b.w, 0.f);
    ((float4*)out)[i] = v;
}

extern "C" void kernel_launch(void* const* d_in, const int* in_sizes, int n_in,
                              void* d_out, int out_size, void* d_ws, size_t ws_size,
                              hipStream_t stream) {
    const float* x       = (const float*)d_in[0];   // [B,N,64]
    const int*   rows    = (const int*)d_in[1];     // [K,E]
    const int*   cols    = (const int*)d_in[2];     // [K,E]
    const float* vals    = (const float*)d_in[3];   // [K,E]
    const float* kernels = (const float*)d_in[4];   // [K,64,64]
    const float* bias    = (const float*)d_in[5];   // [64]

    float* out = (float*)d_out;
    float* h   = (float*)d_ws;                      // [B*N, 64] f32 = 51.2 MB scratch

    const int K = in_sizes[4] / (FDIM * FDIM);      // 4
    const int E = in_sizes[1] / K;                  // 800000
    const int M = in_sizes[0] / FDIM;               // B*N = 200000
    const int N = M / 4;                            // 50000 (B = 4)

    // out accumulates via atomics -> must start at zero (harness poisons 0xAA)
    hipMemsetAsync(out, 0, (size_t)out_size * sizeof(float), stream);

    for (int k = 0; k < K; ++k) {
        gemm64<<<M / 64, 256, 0, stream>>>(
            x, kernels + (size_t)k * FDIM * FDIM, h, M);
        scatter_edges<<<(E + 3) / 4, 256, 0, stream>>>(
            h, rows + (size_t)k * E, cols + (size_t)k * E,
            vals + (size_t)k * E, out, E, N);
    }

    const size_t total4 = (size_t)out_size / 4;
    bias_relu<<<(int)((total4 + 255) / 256), 256, 0, stream>>>(out, bias, total4);
}

// Round 3
// 1048.316 us; speedup vs baseline: 2.6876x; 2.6876x over previous
//
#include <hip/hip_runtime.h>

// GraphConvolution: out = relu(bias + sum_k S_k @ (x @ W_k))
// B=4, N=50000, F_IN=F_OUT=64, K=4, E=800000
//
// Primary path: build CSR per support on-device (histogram + scan + fill),
// then per k: dense GEMM h = x@W_k, then atomic-free gather-accumulate.
// Fallback path (if ws_size can't hold CSR): round-1 atomic scatter.

#define FDIM 64

// ---------------------------------------------------------------------------
// h = x @ W   x:[M,64] f32, W:[64,64] f32, h:[M,64] f32.  M % 64 == 0.
// ---------------------------------------------------------------------------
__global__ __launch_bounds__(256) void gemm64(
    const float* __restrict__ x, const float* __restrict__ W,
    float* __restrict__ h, int M)
{
    __shared__ float xs[64][68];
    __shared__ float Wl[64][64];

    const int t = threadIdx.x;

    {
        const float4* Wv = (const float4*)W;
        float4* Wd = (float4*)&Wl[0][0];
#pragma unroll
        for (int i = 0; i < 4; ++i) Wd[t + 256 * i] = Wv[t + 256 * i];
    }

    const int row0 = blockIdx.x * 64;

#pragma unroll
    for (int i = 0; i < 4; ++i) {
        int idx = t + 256 * i;
        int r = idx >> 4;
        int c4 = idx & 15;
        float4 v = ((const float4*)(x + (size_t)(row0 + r) * FDIM))[c4];
        int f = c4 * 4;
        xs[f + 0][r] = v.x;
        xs[f + 1][r] = v.y;
        xs[f + 2][r] = v.z;
        xs[f + 3][r] = v.w;
    }
    __syncthreads();

    const int r0 = (t >> 4) * 4;
    const int g0 = (t & 15) * 4;

    float acc[4][4];
#pragma unroll
    for (int i = 0; i < 4; ++i)
#pragma unroll
        for (int j = 0; j < 4; ++j) acc[i][j] = 0.f;

#pragma unroll
    for (int f = 0; f < 64; ++f) {
        float4 xv = *(const float4*)&xs[f][r0];
        float4 wv = *(const float4*)&Wl[f][g0];
        acc[0][0] = fmaf(xv.x, wv.x, acc[0][0]);
        acc[0][1] = fmaf(xv.x, wv.y, acc[0][1]);
        acc[0][2] = fmaf(xv.x, wv.z, acc[0][2]);
        acc[0][3] = fmaf(xv.x, wv.w, acc[0][3]);
        acc[1][0] = fmaf(xv.y, wv.x, acc[1][0]);
        acc[1][1] = fmaf(xv.y, wv.y, acc[1][1]);
        acc[1][2] = fmaf(xv.y, wv.z, acc[1][2]);
        acc[1][3] = fmaf(xv.y, wv.w, acc[1][3]);
        acc[2][0] = fmaf(xv.z, wv.x, acc[2][0]);
        acc[2][1] = fmaf(xv.z, wv.y, acc[2][1]);
        acc[2][2] = fmaf(xv.z, wv.z, acc[2][2]);
        acc[2][3] = fmaf(xv.z, wv.w, acc[2][3]);
        acc[3][0] = fmaf(xv.w, wv.x, acc[3][0]);
        acc[3][1] = fmaf(xv.w, wv.y, acc[3][1]);
        acc[3][2] = fmaf(xv.w, wv.z, acc[3][2]);
        acc[3][3] = fmaf(xv.w, wv.w, acc[3][3]);
    }

#pragma unroll
    for (int i = 0; i < 4; ++i) {
        *(float4*)(h + (size_t)(row0 + r0 + i) * FDIM + g0) =
            make_float4(acc[i][0], acc[i][1], acc[i][2], acc[i][3]);
    }
}

// ---------------------------------------------------------------------------
// CSR build
// ---------------------------------------------------------------------------
__global__ __launch_bounds__(256) void hist_rows(
    const int* __restrict__ rows, int* __restrict__ counts,
    int total, int E, int N)
{
    int i = blockIdx.x * 256 + threadIdx.x;
    if (i >= total) return;
    int k = i / E;
    atomicAdd(&counts[k * N + rows[i]], 1);
}

// block-sum per 256-chunk of counts -> bsums[k][nb]
__global__ __launch_bounds__(256) void scan_block_sums(
    const int* __restrict__ counts, int* __restrict__ bsums, int N, int nb)
{
    int k = blockIdx.x / nb, j = blockIdx.x % nb;
    int t = threadIdx.x, lane = t & 63, w = t >> 6;
    int i = j * 256 + t;
    int v = (i < N) ? counts[k * N + i] : 0;
#pragma unroll
    for (int off = 32; off; off >>= 1) v += __shfl_down(v, off);
    __shared__ int lds[4];
    if (lane == 0) lds[w] = v;
    __syncthreads();
    if (t == 0) bsums[k * nb + j] = lds[0] + lds[1] + lds[2] + lds[3];
}

// in-place exclusive scan of bsums[k][0..nb) for each k; single block
__global__ __launch_bounds__(256) void scan_bsums(int* bsums, int nb, int K)
{
    __shared__ int lds[4];
    __shared__ int carry;
    int t = threadIdx.x, lane = t & 63, w = t >> 6;
    for (int k = 0; k < K; ++k) {
        if (t == 0) carry = 0;
        __syncthreads();
        for (int base = 0; base < nb; base += 256) {
            int i = base + t;
            int v = (i < nb) ? bsums[k * nb + i] : 0;
            int x = v;
#pragma unroll
            for (int off = 1; off < 64; off <<= 1) {
                int y = __shfl_up(x, off);
                if (lane >= off) x += y;
            }
            if (lane == 63) lds[w] = x;
            __syncthreads();
            int wo = 0;
            for (int q = 0; q < w; ++q) wo += lds[q];
            int excl = carry + wo + x - v;
            if (i < nb) bsums[k * nb + i] = excl;
            __syncthreads();
            if (t == 255) carry = carry + wo + x;
            __syncthreads();
        }
    }
}

// block-local exclusive scan + block offset -> row_ptr[k][i+1]; row_ptr[k][0]=0
__global__ __launch_bounds__(256) void scan_write_ptr(
    const int* __restrict__ counts, const int* __restrict__ bsums,
    int* __restrict__ row_ptr, int N, int nb)
{
    int k = blockIdx.x / nb, j = blockIdx.x % nb;
    int t = threadIdx.x, lane = t & 63, w = t >> 6;
    int i = j * 256 + t;
    int v = (i < N) ? counts[k * N + i] : 0;
    int x = v;
#pragma unroll
    for (int off = 1; off < 64; off <<= 1) {
        int y = __shfl_up(x, off);
        if (lane >= off) x += y;
    }
    __shared__ int lds[4];
    if (lane == 63) lds[w] = x;
    __syncthreads();
    int wo = 0;
    for (int q = 0; q < w; ++q) wo += lds[q];
    int incl = wo + x;
    if (i < N) row_ptr[k * (N + 1) + i + 1] = bsums[k * nb + j] + incl;
    if (t == 0 && j == 0) row_ptr[k * (N + 1)] = 0;
}

// counts[k][row] still holds the original count; atomicSub hands out slots.
__global__ __launch_bounds__(256) void fill_csr(
    const int* __restrict__ rows, const int* __restrict__ cols,
    const float* __restrict__ vals, const int* __restrict__ row_ptr,
    int* __restrict__ counts, int* __restrict__ csr_col,
    float* __restrict__ csr_val, int total, int E, int N)
{
    int i = blockIdx.x * 256 + threadIdx.x;
    if (i >= total) return;
    int k = i / E;
    int row = rows[i];
    int old = atomicSub(&counts[k * N + row], 1);
    int slot = row_ptr[k * (N + 1) + row] + old - 1;
    csr_col[(size_t)k * E + slot] = cols[i];
    csr_val[(size_t)k * E + slot] = vals[i];
}

// ---------------------------------------------------------------------------
// gather-accumulate: one wave per output row. lane = (b, g4).
// FIRST: out = acc. middle: out += acc. LAST: out = relu(out + acc + bias).
// ---------------------------------------------------------------------------
template <int FIRST, int LAST>
__global__ __launch_bounds__(256) void gather_acc(
    const float* __restrict__ h, const int* __restrict__ row_ptr,
    const int* __restrict__ csr_col, const float* __restrict__ csr_val,
    const float* __restrict__ bias, float* __restrict__ out, int N)
{
    const int wid = (blockIdx.x << 2) | (threadIdx.x >> 6);
    if (wid >= N) return;
    const int lane = threadIdx.x & 63;
    const int b = lane >> 4;
    const int g4 = (lane & 15) << 2;
    const size_t plane = (size_t)N * FDIM;
    const float* hb = h + (size_t)b * plane + g4;

    const int e0 = row_ptr[wid];
    const int e1 = row_ptr[wid + 1];

    float4 acc = make_float4(0.f, 0.f, 0.f, 0.f);

    for (int base = e0; base < e1; base += 64) {
        const int n = min(64, e1 - base);
        int mycol = 0;
        float myval = 0.f;
        if (lane < n) {
            mycol = csr_col[base + lane];
            myval = csr_val[base + lane];
        }
        for (int j = 0; j < n; ++j) {
            int col = __shfl(mycol, j);
            float val = __shfl(myval, j);
            float4 hv = *(const float4*)(hb + (size_t)col * FDIM);
            acc.x = fmaf(hv.x, val, acc.x);
            acc.y = fmaf(hv.y, val, acc.y);
            acc.z = fmaf(hv.z, val, acc.z);
            acc.w = fmaf(hv.w, val, acc.w);
        }
    }

    float* op = out + (size_t)b * plane + (size_t)wid * FDIM + g4;
    if (FIRST) {
        *(float4*)op = acc;
    } else if (!LAST) {
        float4 o = *(const float4*)op;
        o.x += acc.x; o.y += acc.y; o.z += acc.z; o.w += acc.w;
        *(float4*)op = o;
    } else {
        float4 o = *(const float4*)op;
        float4 bi = ((const float4*)bias)[lane & 15];
        o.x = fmaxf(o.x + acc.x + bi.x, 0.f);
        o.y = fmaxf(o.y + acc.y + bi.y, 0.f);
        o.z = fmaxf(o.z + acc.z + bi.z, 0.f);
        o.w = fmaxf(o.w + acc.w + bi.w, 0.f);
        *(float4*)op = o;
    }
}

// ---------------------------------------------------------------------------
// Fallback (round-1): atomic scatter + bias_relu. Used only if ws too small.
// ---------------------------------------------------------------------------
__global__ __launch_bounds__(256) void scatter_edges(
    const float* __restrict__ h,
    const int* __restrict__ rows,
    const int* __restrict__ cols,
    const float* __restrict__ vals,
    float* __restrict__ out,
    int E, int N)
{
    const int e = (blockIdx.x << 2) | (threadIdx.x >> 6);
    if (e >= E) return;
    const int lane = threadIdx.x & 63;

    const int row = __builtin_amdgcn_readfirstlane(rows[e]);
    const int col = __builtin_amdgcn_readfirstlane(cols[e]);
    const float val =
        __uint_as_float(__builtin_amdgcn_readfirstlane(__float_as_uint(vals[e])));

    const size_t stride = (size_t)N * FDIM;
    size_t cbase = (size_t)col * FDIM + lane;
    size_t rbase = (size_t)row * FDIM + lane;

#pragma unroll
    for (int b = 0; b < 4; ++b) {
        float hv = h[cbase + (size_t)b * stride];
        atomicAdd(out + rbase + (size_t)b * stride, hv * val);
    }
}

__global__ __launch_bounds__(256) void bias_relu(
    float* __restrict__ out, const float* __restrict__ bias, size_t total4)
{
    size_t i = (size_t)blockIdx.x * blockDim.x + threadIdx.x;
    if (i >= total4) return;
    float4 v = ((float4*)out)[i];
    float4 b = ((const float4*)bias)[i & 15];
    v.x = fmaxf(v.x + b.x, 0.f);
    v.y = fmaxf(v.y + b.y, 0.f);
    v.z = fmaxf(v.z + b.z, 0.f);
    v.w = fmaxf(v.w + b.w, 0.f);
    ((float4*)out)[i] = v;
}

extern "C" void kernel_launch(void* const* d_in, const int* in_sizes, int n_in,
                              void* d_out, int out_size, void* d_ws, size_t ws_size,
                              hipStream_t stream) {
    const float* x       = (const float*)d_in[0];   // [B,N,64]
    const int*   rows    = (const int*)d_in[1];     // [K,E]
    const int*   cols    = (const int*)d_in[2];     // [K,E]
    const float* vals    = (const float*)d_in[3];   // [K,E]
    const float* kernels = (const float*)d_in[4];   // [K,64,64]
    const float* bias    = (const float*)d_in[5];   // [64]

    float* out = (float*)d_out;

    const int K = in_sizes[4] / (FDIM * FDIM);      // 4
    const int E = in_sizes[1] / K;                  // 800000
    const int M = in_sizes[0] / FDIM;               // B*N = 200000
    const int N = M / 4;                            // 50000 (B=4)
    const int total = K * E;
    const int nb = (N + 255) / 256;

    // ---- workspace layout / requirement ----
    const size_t hB   = (size_t)M * FDIM * sizeof(float);       // 51.2 MB
    const size_t colB = (size_t)total * sizeof(int);            // 12.8 MB
    const size_t valB = (size_t)total * sizeof(float);          // 12.8 MB
    const size_t rpB  = (size_t)K * (N + 1) * sizeof(int);
    const size_t cntB = (size_t)K * N * sizeof(int);
    const size_t bsB  = (size_t)K * nb * sizeof(int);
    const size_t needed = hB + colB + valB + rpB + cntB + bsB + 6 * 16;

    char* ws = (char*)d_ws;
    float* h = (float*)ws;  ws += (hB + 15) & ~(size_t)15;

    if (ws_size >= needed) {
        // ================= CSR gather path =================
        int*   csr_col = (int*)ws;    ws += (colB + 15) & ~(size_t)15;
        float* csr_val = (float*)ws;  ws += (valB + 15) & ~(size_t)15;
        int*   row_ptr = (int*)ws;    ws += (rpB + 15) & ~(size_t)15;
        int*   counts  = (int*)ws;    ws += (cntB + 15) & ~(size_t)15;
        int*   bsums   = (int*)ws;

        hipMemsetAsync(counts, 0, cntB, stream);
        hist_rows<<<(total + 255) / 256, 256, 0, stream>>>(rows, counts, total, E, N);
        scan_block_sums<<<K * nb, 256, 0, stream>>>(counts, bsums, N, nb);
        scan_bsums<<<1, 256, 0, stream>>>(bsums, nb, K);
        scan_write_ptr<<<K * nb, 256, 0, stream>>>(counts, bsums, row_ptr, N, nb);
        fill_csr<<<(total + 255) / 256, 256, 0, stream>>>(
            rows, cols, vals, row_ptr, counts, csr_col, csr_val, total, E, N);

        const int gblocks = (N + 3) / 4;
        for (int k = 0; k < K; ++k) {
            gemm64<<<M / 64, 256, 0, stream>>>(
                x, kernels + (size_t)k * FDIM * FDIM, h, M);
            const int* rp = row_ptr + (size_t)k * (N + 1);
            const int* cc = csr_col + (size_t)k * E;
            const float* cv = csr_val + (size_t)k * E;
            if (k == 0)
                gather_acc<1, 0><<<gblocks, 256, 0, stream>>>(h, rp, cc, cv, bias, out, N);
            else if (k < K - 1)
                gather_acc<0, 0><<<gblocks, 256, 0, stream>>>(h, rp, cc, cv, bias, out, N);
            else
                gather_acc<0, 1><<<gblocks, 256, 0, stream>>>(h, rp, cc, cv, bias, out, N);
        }
        if (K == 1) {  // degenerate: still need bias+relu
            const size_t total4 = (size_t)out_size / 4;
            bias_relu<<<(int)((total4 + 255) / 256), 256, 0, stream>>>(out, bias, total4);
        }
    } else {
        // ================= fallback: atomic scatter (round-1 proven) =========
        hipMemsetAsync(out, 0, (size_t)out_size * sizeof(float), stream);
        for (int k = 0; k < K; ++k) {
            gemm64<<<M / 64, 256, 0, stream>>>(
                x, kernels + (size_t)k * FDIM * FDIM, h, M);
            scatter_edges<<<(E + 3) / 4, 256, 0, stream>>>(
                h, rows + (size_t)k * E, cols + (size_t)k * E,
                vals + (size_t)k * E, out, E, N);
        }
        const size_t total4 = (size_t)out_size / 4;
        bias_relu<<<(int)((total4 + 255) / 256), 256, 0, stream>>>(out, bias, total4);
    }
}

// Round 4
// 731.470 us; speedup vs baseline: 3.8517x; 1.4332x over previous
//
#include <hip/hip_runtime.h>

// GraphConvolution: out = relu(bias + sum_k S_k @ (x @ W_k))
// B=4, N=50000, F_IN=F_OUT=64, K=4, E=800000
//
// Pipeline: build packed CSR once (u32 = col<<16 | bf16(val)), then per
// k-group: gemm_all (h_k in bf16, x read once) + fused gather-accumulate
// (atomic-free; out touched once per group; bias+relu folded into last).

#define FDIM 64

__device__ __forceinline__ unsigned short bf16_rne(float v) {
    unsigned u = __float_as_uint(v);
    return (unsigned short)((u + 0x7FFFu + ((u >> 16) & 1u)) >> 16);
}

// ---------------------------------------------------------------------------
// gemm_all: for kk in [0,kcount): h[kk] = x @ W[kbase+kk], bf16 output.
// x:[M,64] f32 (bn-major), W:[K,64,64], hb:[kcount][M][64] bf16.
// ---------------------------------------------------------------------------
__global__ __launch_bounds__(256) void gemm_all(
    const float* __restrict__ x, const float* __restrict__ kernels,
    unsigned short* __restrict__ hb, int M, int kbase, int kcount)
{
    __shared__ float xs[64][68];
    __shared__ float Wl[64][64];

    const int t = threadIdx.x;
    const int row0 = blockIdx.x * 64;

    // load x tile (coalesced float4), store transposed into xs — once
#pragma unroll
    for (int i = 0; i < 4; ++i) {
        int idx = t + 256 * i;
        int r = idx >> 4;
        int c4 = idx & 15;
        float4 v = ((const float4*)(x + (size_t)(row0 + r) * FDIM))[c4];
        int f = c4 * 4;
        xs[f + 0][r] = v.x;
        xs[f + 1][r] = v.y;
        xs[f + 2][r] = v.z;
        xs[f + 3][r] = v.w;
    }

    const int r0 = (t >> 4) * 4;
    const int g0 = (t & 15) * 4;

    for (int kk = 0; kk < kcount; ++kk) {
        __syncthreads();   // xs ready (kk=0) / previous compute done (kk>0)
        {
            const float4* Wv = (const float4*)(kernels + (size_t)(kbase + kk) * FDIM * FDIM);
            float4* Wd = (float4*)&Wl[0][0];
#pragma unroll
            for (int i = 0; i < 4; ++i) Wd[t + 256 * i] = Wv[t + 256 * i];
        }
        __syncthreads();

        float acc[4][4];
#pragma unroll
        for (int i = 0; i < 4; ++i)
#pragma unroll
            for (int j = 0; j < 4; ++j) acc[i][j] = 0.f;

#pragma unroll
        for (int f = 0; f < 64; ++f) {
            float4 xv = *(const float4*)&xs[f][r0];
            float4 wv = *(const float4*)&Wl[f][g0];
            acc[0][0] = fmaf(xv.x, wv.x, acc[0][0]);
            acc[0][1] = fmaf(xv.x, wv.y, acc[0][1]);
            acc[0][2] = fmaf(xv.x, wv.z, acc[0][2]);
            acc[0][3] = fmaf(xv.x, wv.w, acc[0][3]);
            acc[1][0] = fmaf(xv.y, wv.x, acc[1][0]);
            acc[1][1] = fmaf(xv.y, wv.y, acc[1][1]);
            acc[1][2] = fmaf(xv.y, wv.z, acc[1][2]);
            acc[1][3] = fmaf(xv.y, wv.w, acc[1][3]);
            acc[2][0] = fmaf(xv.z, wv.x, acc[2][0]);
            acc[2][1] = fmaf(xv.z, wv.y, acc[2][1]);
            acc[2][2] = fmaf(xv.z, wv.z, acc[2][2]);
            acc[2][3] = fmaf(xv.z, wv.w, acc[2][3]);
            acc[3][0] = fmaf(xv.w, wv.x, acc[3][0]);
            acc[3][1] = fmaf(xv.w, wv.y, acc[3][1]);
            acc[3][2] = fmaf(xv.w, wv.z, acc[3][2]);
            acc[3][3] = fmaf(xv.w, wv.w, acc[3][3]);
        }

#pragma unroll
        for (int i = 0; i < 4; ++i) {
            ushort4 p;
            p.x = bf16_rne(acc[i][0]);
            p.y = bf16_rne(acc[i][1]);
            p.z = bf16_rne(acc[i][2]);
            p.w = bf16_rne(acc[i][3]);
            *(ushort4*)(hb + ((size_t)kk * M + row0 + r0 + i) * FDIM + g0) = p;
        }
    }
}

// ---------------------------------------------------------------------------
// CSR build (packed payload)
// ---------------------------------------------------------------------------
__global__ __launch_bounds__(256) void hist_rows(
    const int* __restrict__ rows, int* __restrict__ counts,
    int total, int E, int N)
{
    int i = blockIdx.x * 256 + threadIdx.x;
    if (i >= total) return;
    int k = i / E;
    atomicAdd(&counts[k * N + rows[i]], 1);
}

__global__ __launch_bounds__(256) void scan_block_sums(
    const int* __restrict__ counts, int* __restrict__ bsums, int N, int nb)
{
    int k = blockIdx.x / nb, j = blockIdx.x % nb;
    int t = threadIdx.x, lane = t & 63, w = t >> 6;
    int i = j * 256 + t;
    int v = (i < N) ? counts[k * N + i] : 0;
#pragma unroll
    for (int off = 32; off; off >>= 1) v += __shfl_down(v, off);
    __shared__ int lds[4];
    if (lane == 0) lds[w] = v;
    __syncthreads();
    if (t == 0) bsums[k * nb + j] = lds[0] + lds[1] + lds[2] + lds[3];
}

__global__ __launch_bounds__(256) void scan_bsums(int* bsums, int nb, int K)
{
    __shared__ int lds[4];
    __shared__ int carry;
    int t = threadIdx.x, lane = t & 63, w = t >> 6;
    for (int k = 0; k < K; ++k) {
        if (t == 0) carry = 0;
        __syncthreads();
        for (int base = 0; base < nb; base += 256) {
            int i = base + t;
            int v = (i < nb) ? bsums[k * nb + i] : 0;
            int x = v;
#pragma unroll
            for (int off = 1; off < 64; off <<= 1) {
                int y = __shfl_up(x, off);
                if (lane >= off) x += y;
            }
            if (lane == 63) lds[w] = x;
            __syncthreads();
            int wo = 0;
            for (int q = 0; q < w; ++q) wo += lds[q];
            int excl = carry + wo + x - v;
            if (i < nb) bsums[k * nb + i] = excl;
            __syncthreads();
            if (t == 255) carry = carry + wo + x;
            __syncthreads();
        }
    }
}

__global__ __launch_bounds__(256) void scan_write_ptr(
    const int* __restrict__ counts, const int* __restrict__ bsums,
    int* __restrict__ row_ptr, int N, int nb)
{
    int k = blockIdx.x / nb, j = blockIdx.x % nb;
    int t = threadIdx.x, lane = t & 63, w = t >> 6;
    int i = j * 256 + t;
    int v = (i < N) ? counts[k * N + i] : 0;
    int x = v;
#pragma unroll
    for (int off = 1; off < 64; off <<= 1) {
        int y = __shfl_up(x, off);
        if (lane >= off) x += y;
    }
    __shared__ int lds[4];
    if (lane == 63) lds[w] = x;
    __syncthreads();
    int wo = 0;
    for (int q = 0; q < w; ++q) wo += lds[q];
    int incl = wo + x;
    if (i < N) row_ptr[k * (N + 1) + i + 1] = bsums[k * nb + j] + incl;
    if (t == 0 && j == 0) row_ptr[k * (N + 1)] = 0;
}

// packed fill: one u32 per edge = (col<<16) | bf16(val)
__global__ __launch_bounds__(256) void fill_csr_packed(
    const int* __restrict__ rows, const int* __restrict__ cols,
    const float* __restrict__ vals, const int* __restrict__ row_ptr,
    int* __restrict__ counts, unsigned* __restrict__ csr,
    int total, int E, int N)
{
    int i = blockIdx.x * 256 + threadIdx.x;
    if (i >= total) return;
    int k = i / E;
    int row = rows[i];
    int old = atomicSub(&counts[k * N + row], 1);
    int slot = row_ptr[k * (N + 1) + row] + old - 1;
    unsigned pk = ((unsigned)cols[i] << 16) | (unsigned)bf16_rne(vals[i]);
    csr[(size_t)k * E + slot] = pk;
}

// ---------------------------------------------------------------------------
// fused gather: one wave per output row; loops kcount supports.
// lane = (b, c4): b = lane>>4, features c4*4..c4*4+3. Per edge per k:
// 1 shfl broadcast + one coalesced 512B wave read of bf16 h.
// ---------------------------------------------------------------------------
__global__ __launch_bounds__(256) void gather_fused(
    const unsigned short* __restrict__ hb, const int* __restrict__ row_ptr,
    const unsigned* __restrict__ csr, const float* __restrict__ bias,
    float* __restrict__ out, int N, int M, int E,
    int kbase, int kcount, int first, int last)
{
    const int wid = (blockIdx.x << 2) | (threadIdx.x >> 6);
    if (wid >= N) return;
    const int lane = threadIdx.x & 63;
    const int b = lane >> 4;
    const int c4 = lane & 15;

    float4 acc = make_float4(0.f, 0.f, 0.f, 0.f);

    for (int kk = 0; kk < kcount; ++kk) {
        const int* rp = row_ptr + (size_t)(kbase + kk) * (N + 1);
        const unsigned* ck = csr + (size_t)(kbase + kk) * E;
        const unsigned short* hbb =
            hb + ((size_t)kk * M + (size_t)b * N) * FDIM + c4 * 4;

        const int e0 = rp[wid];
        const int e1 = rp[wid + 1];

        for (int base = e0; base < e1; base += 64) {
            const int n = min(64, e1 - base);
            unsigned w = 0;
            if (lane < n) w = ck[base + lane];
            for (int j = 0; j < n; ++j) {
                unsigned ww = __shfl((int)w, j);
                int col = ww >> 16;
                float val = __uint_as_float(ww << 16);
                uint2 hv = *(const uint2*)(hbb + (size_t)col * FDIM);
                float f0 = __uint_as_float(hv.x << 16);
                float f1 = __uint_as_float(hv.x & 0xFFFF0000u);
                float f2 = __uint_as_float(hv.y << 16);
                float f3 = __uint_as_float(hv.y & 0xFFFF0000u);
                acc.x = fmaf(f0, val, acc.x);
                acc.y = fmaf(f1, val, acc.y);
                acc.z = fmaf(f2, val, acc.z);
                acc.w = fmaf(f3, val, acc.w);
            }
        }
    }

    float* op = out + ((size_t)b * N + wid) * FDIM + c4 * 4;
    if (first && last) {
        float4 bi = ((const float4*)bias)[c4];
        float4 o;
        o.x = fmaxf(acc.x + bi.x, 0.f);
        o.y = fmaxf(acc.y + bi.y, 0.f);
        o.z = fmaxf(acc.z + bi.z, 0.f);
        o.w = fmaxf(acc.w + bi.w, 0.f);
        *(float4*)op = o;
    } else if (first) {
        *(float4*)op = acc;
    } else if (!last) {
        float4 o = *(const float4*)op;
        o.x += acc.x; o.y += acc.y; o.z += acc.z; o.w += acc.w;
        *(float4*)op = o;
    } else {
        float4 o = *(const float4*)op;
        float4 bi = ((const float4*)bias)[c4];
        o.x = fmaxf(o.x + acc.x + bi.x, 0.f);
        o.y = fmaxf(o.y + acc.y + bi.y, 0.f);
        o.z = fmaxf(o.z + acc.z + bi.z, 0.f);
        o.w = fmaxf(o.w + acc.w + bi.w, 0.f);
        *(float4*)op = o;
    }
}

// ---------------------------------------------------------------------------
// Tier-3 fallback (round-1 proven): f32 gemm + atomic scatter + bias_relu.
// ---------------------------------------------------------------------------
__global__ __launch_bounds__(256) void gemm64(
    const float* __restrict__ x, const float* __restrict__ W,
    float* __restrict__ h, int M)
{
    __shared__ float xs[64][68];
    __shared__ float Wl[64][64];
    const int t = threadIdx.x;
    {
        const float4* Wv = (const float4*)W;
        float4* Wd = (float4*)&Wl[0][0];
#pragma unroll
        for (int i = 0; i < 4; ++i) Wd[t + 256 * i] = Wv[t + 256 * i];
    }
    const int row0 = blockIdx.x * 64;
#pragma unroll
    for (int i = 0; i < 4; ++i) {
        int idx = t + 256 * i;
        int r = idx >> 4;
        int c4 = idx & 15;
        float4 v = ((const float4*)(x + (size_t)(row0 + r) * FDIM))[c4];
        int f = c4 * 4;
        xs[f + 0][r] = v.x; xs[f + 1][r] = v.y;
        xs[f + 2][r] = v.z; xs[f + 3][r] = v.w;
    }
    __syncthreads();
    const int r0 = (t >> 4) * 4;
    const int g0 = (t & 15) * 4;
    float acc[4][4];
#pragma unroll
    for (int i = 0; i < 4; ++i)
#pragma unroll
        for (int j = 0; j < 4; ++j) acc[i][j] = 0.f;
#pragma unroll
    for (int f = 0; f < 64; ++f) {
        float4 xv = *(const float4*)&xs[f][r0];
        float4 wv = *(const float4*)&Wl[f][g0];
        acc[0][0] = fmaf(xv.x, wv.x, acc[0][0]); acc[0][1] = fmaf(xv.x, wv.y, acc[0][1]);
        acc[0][2] = fmaf(xv.x, wv.z, acc[0][2]); acc[0][3] = fmaf(xv.x, wv.w, acc[0][3]);
        acc[1][0] = fmaf(xv.y, wv.x, acc[1][0]); acc[1][1] = fmaf(xv.y, wv.y, acc[1][1]);
        acc[1][2] = fmaf(xv.y, wv.z, acc[1][2]); acc[1][3] = fmaf(xv.y, wv.w, acc[1][3]);
        acc[2][0] = fmaf(xv.z, wv.x, acc[2][0]); acc[2][1] = fmaf(xv.z, wv.y, acc[2][1]);
        acc[2][2] = fmaf(xv.z, wv.z, acc[2][2]); acc[2][3] = fmaf(xv.z, wv.w, acc[2][3]);
        acc[3][0] = fmaf(xv.w, wv.x, acc[3][0]); acc[3][1] = fmaf(xv.w, wv.y, acc[3][1]);
        acc[3][2] = fmaf(xv.w, wv.z, acc[3][2]); acc[3][3] = fmaf(xv.w, wv.w, acc[3][3]);
    }
#pragma unroll
    for (int i = 0; i < 4; ++i)
        *(float4*)(h + (size_t)(row0 + r0 + i) * FDIM + g0) =
            make_float4(acc[i][0], acc[i][1], acc[i][2], acc[i][3]);
}

__global__ __launch_bounds__(256) void scatter_edges(
    const float* __restrict__ h, const int* __restrict__ rows,
    const int* __restrict__ cols, const float* __restrict__ vals,
    float* __restrict__ out, int E, int N)
{
    const int e = (blockIdx.x << 2) | (threadIdx.x >> 6);
    if (e >= E) return;
    const int lane = threadIdx.x & 63;
    const int row = __builtin_amdgcn_readfirstlane(rows[e]);
    const int col = __builtin_amdgcn_readfirstlane(cols[e]);
    const float val =
        __uint_as_float(__builtin_amdgcn_readfirstlane(__float_as_uint(vals[e])));
    const size_t stride = (size_t)N * FDIM;
    size_t cbase = (size_t)col * FDIM + lane;
    size_t rbase = (size_t)row * FDIM + lane;
#pragma unroll
    for (int b = 0; b < 4; ++b) {
        float hv = h[cbase + (size_t)b * stride];
        atomicAdd(out + rbase + (size_t)b * stride, hv * val);
    }
}

__global__ __launch_bounds__(256) void bias_relu(
    float* __restrict__ out, const float* __restrict__ bias, size_t total4)
{
    size_t i = (size_t)blockIdx.x * blockDim.x + threadIdx.x;
    if (i >= total4) return;
    float4 v = ((float4*)out)[i];
    float4 b = ((const float4*)bias)[i & 15];
    v.x = fmaxf(v.x + b.x, 0.f); v.y = fmaxf(v.y + b.y, 0.f);
    v.z = fmaxf(v.z + b.z, 0.f); v.w = fmaxf(v.w + b.w, 0.f);
    ((float4*)out)[i] = v;
}

extern "C" void kernel_launch(void* const* d_in, const int* in_sizes, int n_in,
                              void* d_out, int out_size, void* d_ws, size_t ws_size,
                              hipStream_t stream) {
    const float* x       = (const float*)d_in[0];
    const int*   rows    = (const int*)d_in[1];
    const int*   cols    = (const int*)d_in[2];
    const float* vals    = (const float*)d_in[3];
    const float* kernels = (const float*)d_in[4];
    const float* bias    = (const float*)d_in[5];

    float* out = (float*)d_out;

    const int K = in_sizes[4] / (FDIM * FDIM);      // 4
    const int E = in_sizes[1] / K;                  // 800000
    const int M = in_sizes[0] / FDIM;               // B*N = 200000
    const int N = M / 4;                            // 50000 (B=4)
    const int total = K * E;
    const int nb = (N + 255) / 256;

    const size_t al = 15;
    const size_t csrB = ((size_t)total * 4 + al) & ~al;            // 12.8 MB
    const size_t rpB  = ((size_t)K * (N + 1) * 4 + al) & ~al;
    const size_t cntB = ((size_t)K * N * 4 + al) & ~al;
    const size_t bsB  = ((size_t)K * nb * 4 + al) & ~al;
    const size_t baseB = csrB + rpB + cntB + bsB;
    const size_t planeB = (size_t)M * FDIM * 2;                    // bf16 plane 25.6 MB

    // choose k-group size G: largest of {4,2,1} whose h-buffer fits
    int G = 0;
    if (ws_size >= baseB + 4 * planeB) G = 4;
    else if (ws_size >= baseB + 2 * planeB) G = 2;
    else if (ws_size >= baseB + 1 * planeB) G = 1;

    if (G > 0) {
        char* ws = (char*)d_ws;
        unsigned short* hb = (unsigned short*)ws;  ws += (size_t)G * planeB;
        unsigned* csr      = (unsigned*)ws;        ws += csrB;
        int* row_ptr       = (int*)ws;             ws += rpB;
        int* counts        = (int*)ws;             ws += cntB;
        int* bsums         = (int*)ws;

        hipMemsetAsync(counts, 0, (size_t)K * N * 4, stream);
        hist_rows<<<(total + 255) / 256, 256, 0, stream>>>(rows, counts, total, E, N);
        scan_block_sums<<<K * nb, 256, 0, stream>>>(counts, bsums, N, nb);
        scan_bsums<<<1, 256, 0, stream>>>(bsums, nb, K);
        scan_write_ptr<<<K * nb, 256, 0, stream>>>(counts, bsums, row_ptr, N, nb);
        fill_csr_packed<<<(total + 255) / 256, 256, 0, stream>>>(
            rows, cols, vals, row_ptr, counts, csr, total, E, N);

        const int gblocks = (N + 3) / 4;
        for (int kb = 0; kb < K; kb += G) {
            const int kc = (kb + G <= K) ? G : (K - kb);
            gemm_all<<<M / 64, 256, 0, stream>>>(x, kernels, hb, M, kb, kc);
            gather_fused<<<gblocks, 256, 0, stream>>>(
                hb, row_ptr, csr, bias, out, N, M, E,
                kb, kc, kb == 0 ? 1 : 0, (kb + kc == K) ? 1 : 0);
        }
    } else {
        // Tier-3 fallback: atomic scatter (round-1 proven)
        float* h = (float*)d_ws;
        hipMemsetAsync(out, 0, (size_t)out_size * sizeof(float), stream);
        for (int k = 0; k < K; ++k) {
            gemm64<<<M / 64, 256, 0, stream>>>(
                x, kernels + (size_t)k * FDIM * FDIM, h, M);
            scatter_edges<<<(E + 3) / 4, 256, 0, stream>>>(
                h, rows + (size_t)k * E, cols + (size_t)k * E,
                vals + (size_t)k * E, out, E, N);
        }
        const size_t total4 = (size_t)out_size / 4;
        bias_relu<<<(int)((total4 + 255) / 256), 256, 0, stream>>>(out, bias, total4);
    }
}

// Round 5
// 724.629 us; speedup vs baseline: 3.8881x; 1.0094x over previous
//
#include <hip/hip_runtime.h>

// GraphConvolution: out = relu(bias + sum_k S_k @ (x @ W_k))
// B=4, N=50000, F_IN=F_OUT=64, K=4, E=800000
//
// Pipeline: build packed CSR once (u32 = col<<16 | bf16(val)), then per
// k-group: gemm_all (h in bf16, INTERLEAVED [n][b][f] layout -> one
// contiguous 512B wave read per edge) + fused gather-accumulate
// (atomic-free; out touched once per group; bias+relu folded into last).

#define FDIM 64

__device__ __forceinline__ unsigned short bf16_rne(float v) {
    unsigned u = __float_as_uint(v);
    return (unsigned short)((u + 0x7FFFu + ((u >> 16) & 1u)) >> 16);
}

// ---------------------------------------------------------------------------
// gemm_all: for kk in [0,kcount): h[kk] = x @ W[kbase+kk], bf16 output in
// interleaved layout hb[kk][n][b][f] (512 B per (kk,n)).
// x:[M=B*N,64] f32 (b-major rows), W:[K,64,64].
// ---------------------------------------------------------------------------
__global__ __launch_bounds__(256) void gemm_all(
    const float* __restrict__ x, const float* __restrict__ kernels,
    unsigned short* __restrict__ hb, int M, int N, int kbase, int kcount)
{
    __shared__ float xs[64][68];
    __shared__ float Wl[64][64];

    const int t = threadIdx.x;
    const int row0 = blockIdx.x * 64;

    // load x tile (coalesced float4), store transposed into xs — once
#pragma unroll
    for (int i = 0; i < 4; ++i) {
        int idx = t + 256 * i;
        int r = idx >> 4;
        int c4 = idx & 15;
        float4 v = ((const float4*)(x + (size_t)(row0 + r) * FDIM))[c4];
        int f = c4 * 4;
        xs[f + 0][r] = v.x;
        xs[f + 1][r] = v.y;
        xs[f + 2][r] = v.z;
        xs[f + 3][r] = v.w;
    }

    const int r0 = (t >> 4) * 4;
    const int g0 = (t & 15) * 4;

    // precompute interleaved store offsets for my 4 rows (b = row/N, n = row%N)
    size_t off[4];
#pragma unroll
    for (int i = 0; i < 4; ++i) {
        int row = row0 + r0 + i;
        int b = row / N;
        int n = row - b * N;
        off[i] = (size_t)n * 256 + (size_t)b * 64 + g0;   // ushort units
    }
    const size_t planeU = (size_t)N * 256;                 // ushorts per kk

    for (int kk = 0; kk < kcount; ++kk) {
        __syncthreads();   // xs ready (kk=0) / previous compute done (kk>0)
        {
            const float4* Wv = (const float4*)(kernels + (size_t)(kbase + kk) * FDIM * FDIM);
            float4* Wd = (float4*)&Wl[0][0];
#pragma unroll
            for (int i = 0; i < 4; ++i) Wd[t + 256 * i] = Wv[t + 256 * i];
        }
        __syncthreads();

        float acc[4][4];
#pragma unroll
        for (int i = 0; i < 4; ++i)
#pragma unroll
            for (int j = 0; j < 4; ++j) acc[i][j] = 0.f;

#pragma unroll
        for (int f = 0; f < 64; ++f) {
            float4 xv = *(const float4*)&xs[f][r0];
            float4 wv = *(const float4*)&Wl[f][g0];
            acc[0][0] = fmaf(xv.x, wv.x, acc[0][0]);
            acc[0][1] = fmaf(xv.x, wv.y, acc[0][1]);
            acc[0][2] = fmaf(xv.x, wv.z, acc[0][2]);
            acc[0][3] = fmaf(xv.x, wv.w, acc[0][3]);
            acc[1][0] = fmaf(xv.y, wv.x, acc[1][0]);
            acc[1][1] = fmaf(xv.y, wv.y, acc[1][1]);
            acc[1][2] = fmaf(xv.y, wv.z, acc[1][2]);
            acc[1][3] = fmaf(xv.y, wv.w, acc[1][3]);
            acc[2][0] = fmaf(xv.z, wv.x, acc[2][0]);
            acc[2][1] = fmaf(xv.z, wv.y, acc[2][1]);
            acc[2][2] = fmaf(xv.z, wv.z, acc[2][2]);
            acc[2][3] = fmaf(xv.z, wv.w, acc[2][3]);
            acc[3][0] = fmaf(xv.w, wv.x, acc[3][0]);
            acc[3][1] = fmaf(xv.w, wv.y, acc[3][1]);
            acc[3][2] = fmaf(xv.w, wv.z, acc[3][2]);
            acc[3][3] = fmaf(xv.w, wv.w, acc[3][3]);
        }

        unsigned short* hk = hb + (size_t)kk * planeU;
#pragma unroll
        for (int i = 0; i < 4; ++i) {
            ushort4 p;
            p.x = bf16_rne(acc[i][0]);
            p.y = bf16_rne(acc[i][1]);
            p.z = bf16_rne(acc[i][2]);
            p.w = bf16_rne(acc[i][3]);
            *(ushort4*)(hk + off[i]) = p;
        }
    }
}

// ---------------------------------------------------------------------------
// CSR build (packed payload)
// ---------------------------------------------------------------------------
__global__ __launch_bounds__(256) void hist_rows(
    const int* __restrict__ rows, int* __restrict__ counts,
    int total, int E, int N)
{
    int i = blockIdx.x * 256 + threadIdx.x;
    if (i >= total) return;
    int k = i / E;
    atomicAdd(&counts[k * N + rows[i]], 1);
}

__global__ __launch_bounds__(256) void scan_block_sums(
    const int* __restrict__ counts, int* __restrict__ bsums, int N, int nb)
{
    int k = blockIdx.x / nb, j = blockIdx.x % nb;
    int t = threadIdx.x, lane = t & 63, w = t >> 6;
    int i = j * 256 + t;
    int v = (i < N) ? counts[k * N + i] : 0;
#pragma unroll
    for (int off = 32; off; off >>= 1) v += __shfl_down(v, off);
    __shared__ int lds[4];
    if (lane == 0) lds[w] = v;
    __syncthreads();
    if (t == 0) bsums[k * nb + j] = lds[0] + lds[1] + lds[2] + lds[3];
}

__global__ __launch_bounds__(256) void scan_bsums(int* bsums, int nb, int K)
{
    __shared__ int lds[4];
    __shared__ int carry;
    int t = threadIdx.x, lane = t & 63, w = t >> 6;
    for (int k = 0; k < K; ++k) {
        if (t == 0) carry = 0;
        __syncthreads();
        for (int base = 0; base < nb; base += 256) {
            int i = base + t;
            int v = (i < nb) ? bsums[k * nb + i] : 0;
            int x = v;
#pragma unroll
            for (int off = 1; off < 64; off <<= 1) {
                int y = __shfl_up(x, off);
                if (lane >= off) x += y;
            }
            if (lane == 63) lds[w] = x;
            __syncthreads();
            int wo = 0;
            for (int q = 0; q < w; ++q) wo += lds[q];
            int excl = carry + wo + x - v;
            if (i < nb) bsums[k * nb + i] = excl;
            __syncthreads();
            if (t == 255) carry = carry + wo + x;
            __syncthreads();
        }
    }
}

__global__ __launch_bounds__(256) void scan_write_ptr(
    const int* __restrict__ counts, const int* __restrict__ bsums,
    int* __restrict__ row_ptr, int N, int nb)
{
    int k = blockIdx.x / nb, j = blockIdx.x % nb;
    int t = threadIdx.x, lane = t & 63, w = t >> 6;
    int i = j * 256 + t;
    int v = (i < N) ? counts[k * N + i] : 0;
    int x = v;
#pragma unroll
    for (int off = 1; off < 64; off <<= 1) {
        int y = __shfl_up(x, off);
        if (lane >= off) x += y;
    }
    __shared__ int lds[4];
    if (lane == 63) lds[w] = x;
    __syncthreads();
    int wo = 0;
    for (int q = 0; q < w; ++q) wo += lds[q];
    int incl = wo + x;
    if (i < N) row_ptr[k * (N + 1) + i + 1] = bsums[k * nb + j] + incl;
    if (t == 0 && j == 0) row_ptr[k * (N + 1)] = 0;
}

// packed fill: one u32 per edge = (col<<16) | bf16(val)
__global__ __launch_bounds__(256) void fill_csr_packed(
    const int* __restrict__ rows, const int* __restrict__ cols,
    const float* __restrict__ vals, const int* __restrict__ row_ptr,
    int* __restrict__ counts, unsigned* __restrict__ csr,
    int total, int E, int N)
{
    int i = blockIdx.x * 256 + threadIdx.x;
    if (i >= total) return;
    int k = i / E;
    int row = rows[i];
    int old = atomicSub(&counts[k * N + row], 1);
    int slot = row_ptr[k * (N + 1) + row] + old - 1;
    unsigned pk = ((unsigned)cols[i] << 16) | (unsigned)bf16_rne(vals[i]);
    csr[(size_t)k * E + slot] = pk;
}

// ---------------------------------------------------------------------------
// fused gather: one wave per output row; loops kcount supports.
// lane l = (b = l>>4, f4 = l&15). h is interleaved [n][b][f] so the wave's
// per-edge read is ONE contiguous 512 B block: addr = col*512 + l*8.
// ---------------------------------------------------------------------------
__global__ __launch_bounds__(256) void gather_fused(
    const unsigned short* __restrict__ hb, const int* __restrict__ row_ptr,
    const unsigned* __restrict__ csr, const float* __restrict__ bias,
    float* __restrict__ out, int N, int E,
    int kbase, int kcount, int first, int last)
{
    const int wid = (blockIdx.x << 2) | (threadIdx.x >> 6);
    if (wid >= N) return;
    const int lane = threadIdx.x & 63;
    const int b = lane >> 4;
    const int c4 = lane & 15;
    const size_t planeU = (size_t)N * 256;

    float4 acc = make_float4(0.f, 0.f, 0.f, 0.f);

    for (int kk = 0; kk < kcount; ++kk) {
        const int* rp = row_ptr + (size_t)(kbase + kk) * (N + 1);
        const unsigned* ck = csr + (size_t)(kbase + kk) * E;
        const unsigned short* hbb = hb + (size_t)kk * planeU + lane * 4;

        const int e0 = rp[wid];
        const int e1 = rp[wid + 1];

        for (int base = e0; base < e1; base += 64) {
            const int n = min(64, e1 - base);
            unsigned w = 0;
            if (lane < n) w = ck[base + lane];
#pragma unroll 4
            for (int j = 0; j < n; ++j) {
                unsigned ww = __shfl((int)w, j);
                int col = ww >> 16;
                float val = __uint_as_float(ww << 16);
                uint2 hv = *(const uint2*)(hbb + (size_t)col * 256);
                float f0 = __uint_as_float(hv.x << 16);
                float f1 = __uint_as_float(hv.x & 0xFFFF0000u);
                float f2 = __uint_as_float(hv.y << 16);
                float f3 = __uint_as_float(hv.y & 0xFFFF0000u);
                acc.x = fmaf(f0, val, acc.x);
                acc.y = fmaf(f1, val, acc.y);
                acc.z = fmaf(f2, val, acc.z);
                acc.w = fmaf(f3, val, acc.w);
            }
        }
    }

    float* op = out + ((size_t)b * N + wid) * FDIM + c4 * 4;
    if (first && last) {
        float4 bi = ((const float4*)bias)[c4];
        float4 o;
        o.x = fmaxf(acc.x + bi.x, 0.f);
        o.y = fmaxf(acc.y + bi.y, 0.f);
        o.z = fmaxf(acc.z + bi.z, 0.f);
        o.w = fmaxf(acc.w + bi.w, 0.f);
        *(float4*)op = o;
    } else if (first) {
        *(float4*)op = acc;
    } else if (!last) {
        float4 o = *(const float4*)op;
        o.x += acc.x; o.y += acc.y; o.z += acc.z; o.w += acc.w;
        *(float4*)op = o;
    } else {
        float4 o = *(const float4*)op;
        float4 bi = ((const float4*)bias)[c4];
        o.x = fmaxf(o.x + acc.x + bi.x, 0.f);
        o.y = fmaxf(o.y + acc.y + bi.y, 0.f);
        o.z = fmaxf(o.z + acc.z + bi.z, 0.f);
        o.w = fmaxf(o.w + acc.w + bi.w, 0.f);
        *(float4*)op = o;
    }
}

// ---------------------------------------------------------------------------
// Tier-3 fallback (round-1 proven): f32 gemm + atomic scatter + bias_relu.
// ---------------------------------------------------------------------------
__global__ __launch_bounds__(256) void gemm64(
    const float* __restrict__ x, const float* __restrict__ W,
    float* __restrict__ h, int M)
{
    __shared__ float xs[64][68];
    __shared__ float Wl[64][64];
    const int t = threadIdx.x;
    {
        const float4* Wv = (const float4*)W;
        float4* Wd = (float4*)&Wl[0][0];
#pragma unroll
        for (int i = 0; i < 4; ++i) Wd[t + 256 * i] = Wv[t + 256 * i];
    }
    const int row0 = blockIdx.x * 64;
#pragma unroll
    for (int i = 0; i < 4; ++i) {
        int idx = t + 256 * i;
        int r = idx >> 4;
        int c4 = idx & 15;
        float4 v = ((const float4*)(x + (size_t)(row0 + r) * FDIM))[c4];
        int f = c4 * 4;
        xs[f + 0][r] = v.x; xs[f + 1][r] = v.y;
        xs[f + 2][r] = v.z; xs[f + 3][r] = v.w;
    }
    __syncthreads();
    const int r0 = (t >> 4) * 4;
    const int g0 = (t & 15) * 4;
    float acc[4][4];
#pragma unroll
    for (int i = 0; i < 4; ++i)
#pragma unroll
        for (int j = 0; j < 4; ++j) acc[i][j] = 0.f;
#pragma unroll
    for (int f = 0; f < 64; ++f) {
        float4 xv = *(const float4*)&xs[f][r0];
        float4 wv = *(const float4*)&Wl[f][g0];
        acc[0][0] = fmaf(xv.x, wv.x, acc[0][0]); acc[0][1] = fmaf(xv.x, wv.y, acc[0][1]);
        acc[0][2] = fmaf(xv.x, wv.z, acc[0][2]); acc[0][3] = fmaf(xv.x, wv.w, acc[0][3]);
        acc[1][0] = fmaf(xv.y, wv.x, acc[1][0]); acc[1][1] = fmaf(xv.y, wv.y, acc[1][1]);
        acc[1][2] = fmaf(xv.y, wv.z, acc[1][2]); acc[1][3] = fmaf(xv.y, wv.w, acc[1][3]);
        acc[2][0] = fmaf(xv.z, wv.x, acc[2][0]); acc[2][1] = fmaf(xv.z, wv.y, acc[2][1]);
        acc[2][2] = fmaf(xv.z, wv.z, acc[2][2]); acc[2][3] = fmaf(xv.z, wv.w, acc[2][3]);
        acc[3][0] = fmaf(xv.w, wv.x, acc[3][0]); acc[3][1] = fmaf(xv.w, wv.y, acc[3][1]);
        acc[3][2] = fmaf(xv.w, wv.z, acc[3][2]); acc[3][3] = fmaf(xv.w, wv.w, acc[3][3]);
    }
#pragma unroll
    for (int i = 0; i < 4; ++i)
        *(float4*)(h + (size_t)(row0 + r0 + i) * FDIM + g0) =
            make_float4(acc[i][0], acc[i][1], acc[i][2], acc[i][3]);
}

__global__ __launch_bounds__(256) void scatter_edges(
    const float* __restrict__ h, const int* __restrict__ rows,
    const int* __restrict__ cols, const float* __restrict__ vals,
    float* __restrict__ out, int E, int N)
{
    const int e = (blockIdx.x << 2) | (threadIdx.x >> 6);
    if (e >= E) return;
    const int lane = threadIdx.x & 63;
    const int row = __builtin_amdgcn_readfirstlane(rows[e]);
    const int col = __builtin_amdgcn_readfirstlane(cols[e]);
    const float val =
        __uint_as_float(__builtin_amdgcn_readfirstlane(__float_as_uint(vals[e])));
    const size_t stride = (size_t)N * FDIM;
    size_t cbase = (size_t)col * FDIM + lane;
    size_t rbase = (size_t)row * FDIM + lane;
#pragma unroll
    for (int b = 0; b < 4; ++b) {
        float hv = h[cbase + (size_t)b * stride];
        atomicAdd(out + rbase + (size_t)b * stride, hv * val);
    }
}

__global__ __launch_bounds__(256) void bias_relu(
    float* __restrict__ out, const float* __restrict__ bias, size_t total4)
{
    size_t i = (size_t)blockIdx.x * blockDim.x + threadIdx.x;
    if (i >= total4) return;
    float4 v = ((float4*)out)[i];
    float4 b = ((const float4*)bias)[i & 15];
    v.x = fmaxf(v.x + b.x, 0.f); v.y = fmaxf(v.y + b.y, 0.f);
    v.z = fmaxf(v.z + b.z, 0.f); v.w = fmaxf(v.w + b.w, 0.f);
    ((float4*)out)[i] = v;
}

extern "C" void kernel_launch(void* const* d_in, const int* in_sizes, int n_in,
                              void* d_out, int out_size, void* d_ws, size_t ws_size,
                              hipStream_t stream) {
    const float* x       = (const float*)d_in[0];
    const int*   rows    = (const int*)d_in[1];
    const int*   cols    = (const int*)d_in[2];
    const float* vals    = (const float*)d_in[3];
    const float* kernels = (const float*)d_in[4];
    const float* bias    = (const float*)d_in[5];

    float* out = (float*)d_out;

    const int K = in_sizes[4] / (FDIM * FDIM);      // 4
    const int E = in_sizes[1] / K;                  // 800000
    const int M = in_sizes[0] / FDIM;               // B*N = 200000
    const int N = M / 4;                            // 50000 (B=4)
    const int total = K * E;
    const int nb = (N + 255) / 256;

    const size_t al = 15;
    const size_t csrB = ((size_t)total * 4 + al) & ~al;            // 12.8 MB
    const size_t rpB  = ((size_t)K * (N + 1) * 4 + al) & ~al;
    const size_t cntB = ((size_t)K * N * 4 + al) & ~al;
    const size_t bsB  = ((size_t)K * nb * 4 + al) & ~al;
    const size_t baseB = csrB + rpB + cntB + bsB;
    const size_t planeB = (size_t)M * FDIM * 2;                    // bf16 plane 25.6 MB

    // choose k-group size G: largest of {4,2,1} whose h-buffer fits
    int G = 0;
    if (ws_size >= baseB + 4 * planeB) G = 4;
    else if (ws_size >= baseB + 2 * planeB) G = 2;
    else if (ws_size >= baseB + 1 * planeB) G = 1;

    if (G > 0) {
        char* ws = (char*)d_ws;
        unsigned short* hb = (unsigned short*)ws;  ws += (size_t)G * planeB;
        unsigned* csr      = (unsigned*)ws;        ws += csrB;
        int* row_ptr       = (int*)ws;             ws += rpB;
        int* counts        = (int*)ws;             ws += cntB;
        int* bsums         = (int*)ws;

        hipMemsetAsync(counts, 0, (size_t)K * N * 4, stream);
        hist_rows<<<(total + 255) / 256, 256, 0, stream>>>(rows, counts, total, E, N);
        scan_block_sums<<<K * nb, 256, 0, stream>>>(counts, bsums, N, nb);
        scan_bsums<<<1, 256, 0, stream>>>(bsums, nb, K);
        scan_write_ptr<<<K * nb, 256, 0, stream>>>(counts, bsums, row_ptr, N, nb);
        fill_csr_packed<<<(total + 255) / 256, 256, 0, stream>>>(
            rows, cols, vals, row_ptr, counts, csr, total, E, N);

        const int gblocks = (N + 3) / 4;
        for (int kb = 0; kb < K; kb += G) {
            const int kc = (kb + G <= K) ? G : (K - kb);
            gemm_all<<<M / 64, 256, 0, stream>>>(x, kernels, hb, M, N, kb, kc);
            gather_fused<<<gblocks, 256, 0, stream>>>(
                hb, row_ptr, csr, bias, out, N, E,
                kb, kc, kb == 0 ? 1 : 0, (kb + kc == K) ? 1 : 0);
        }
    } else {
        // Tier-3 fallback: atomic scatter (round-1 proven)
        float* h = (float*)d_ws;
        hipMemsetAsync(out, 0, (size_t)out_size * sizeof(float), stream);
        for (int k = 0; k < K; ++k) {
            gemm64<<<M / 64, 256, 0, stream>>>(
                x, kernels + (size_t)k * FDIM * FDIM, h, M);
            scatter_edges<<<(E + 3) / 4, 256, 0, stream>>>(
                h, rows + (size_t)k * E, cols + (size_t)k * E,
                vals + (size_t)k * E, out, E, N);
        }
        const size_t total4 = (size_t)out_size / 4;
        bias_relu<<<(int)((total4 + 255) / 256), 256, 0, stream>>>(out, bias, total4);
    }
}